// Round 12
// baseline (954.383 us; speedup 1.0000x reference)
//
#include <hip/hip_runtime.h>

#define NN 50000
#define NE 800000
#define DD 128
#define RR 8
#define MB (NN * RR)          // 400000 buckets keyed by (dst, r)
#define SCAN_BLK 2048
#define NBLK ((MB + SCAN_BLK - 1) / SCAN_BLK)   // 196

#define HT64 391              // 64-row tiles per half
#define HROWS (HT64 * 64)     // 25024 rows per half

typedef __attribute__((ext_vector_type(8))) short short8;
typedef __attribute__((ext_vector_type(4))) float f32x4;

__device__ __forceinline__ unsigned short f2bf(float f)
{
    unsigned int u = __float_as_uint(f);
    u = (u + 0x7FFFu + ((u >> 16) & 1u)) >> 16;   // RNE
    return (unsigned short)u;
}
__device__ __forceinline__ float bflo(unsigned int p) { return __uint_as_float(p << 16); }
__device__ __forceinline__ float bfhi(unsigned int p) { return __uint_as_float(p & 0xFFFF0000u); }

// ---------------- count per (dst, relation); atomic return = edge rank ----------------
__global__ __launch_bounds__(256) void k_count(const int* __restrict__ ei,
                                               const int* __restrict__ et,
                                               int* __restrict__ cnt,
                                               unsigned short* __restrict__ rank16)
{
    int e = blockIdx.x * 256 + threadIdx.x;
    if (e < NE) {
        int r = et[e];
        int dst = ei[NE + e];
        int old = atomicAdd(&cnt[dst * RR + r], 1);
        rank16[e] = (unsigned short)old;
    }
}

// ---------------- exclusive scan over cnt -> off ----------------
__global__ __launch_bounds__(256) void k_scan1(const int* __restrict__ cnt,
                                               int* __restrict__ off,
                                               int* __restrict__ bsum)
{
    __shared__ int lds[256];
    int t = threadIdx.x;
    int base = blockIdx.x * SCAN_BLK + t * 8;
    int v[8], s = 0;
    #pragma unroll
    for (int j = 0; j < 8; j++) {
        int idx = base + j;
        v[j] = (idx < MB) ? cnt[idx] : 0;
        s += v[j];
    }
    lds[t] = s;
    __syncthreads();
    for (int d = 1; d < 256; d <<= 1) {
        int u = (t >= d) ? lds[t - d] : 0;
        __syncthreads();
        lds[t] += u;
        __syncthreads();
    }
    if (t == 255) bsum[blockIdx.x] = lds[255];
    int run = lds[t] - s;
    #pragma unroll
    for (int j = 0; j < 8; j++) {
        int idx = base + j;
        if (idx < MB) off[idx] = run;
        run += v[j];
    }
}

__global__ __launch_bounds__(256) void k_scan2(const int* __restrict__ bsum,
                                               int* __restrict__ carry)
{
    __shared__ int lds[256];
    int t = threadIdx.x;
    int s = (t < NBLK) ? bsum[t] : 0;
    lds[t] = s;
    __syncthreads();
    for (int d = 1; d < 256; d <<= 1) {
        int u = (t >= d) ? lds[t - d] : 0;
        __syncthreads();
        lds[t] += u;
        __syncthreads();
    }
    if (t < NBLK) carry[t] = lds[t] - s;
}

__global__ __launch_bounds__(256) void k_scan3(int* __restrict__ off,
                                               const int* __restrict__ carry)
{
    int c = carry[blockIdx.x];
    int base = blockIdx.x * SCAN_BLK + threadIdx.x * 8;
    #pragma unroll
    for (int j = 0; j < 8; j++) {
        int idx = base + j;
        if (idx < MB) off[idx] += c;
    }
    if (blockIdx.x == 0 && threadIdx.x == 0) off[MB] = NE;   // sentinel
}

// ---------------- place edges into CSR slots: NO atomics (rank precomputed) ----------------
__global__ __launch_bounds__(256) void k_place(const int* __restrict__ ei,
                                               const int* __restrict__ et,
                                               const int* __restrict__ off,
                                               const unsigned short* __restrict__ rank16,
                                               unsigned short* __restrict__ srt16)
{
    int e = blockIdx.x * 256 + threadIdx.x;
    if (e < NE) {
        int b = ei[NE + e] * RR + et[e];
        srt16[off[b] + (int)rank16[e]] = (unsigned short)ei[e];   // src < 50000 < 65536
    }
}

// ---------------- f32 -> bf16 convert (vectorized) ----------------
__global__ __launch_bounds__(256) void k_tobf16(const float* __restrict__ x,
                                                unsigned short* __restrict__ xb, int n4)
{
    int i = blockIdx.x * 256 + threadIdx.x;
    if (i < n4) {
        float4 v = ((const float4*)x)[i];
        uint2 o;
        o.x = (unsigned int)f2bf(v.x) | ((unsigned int)f2bf(v.y) << 16);
        o.y = (unsigned int)f2bf(v.z) | ((unsigned int)f2bf(v.w) << 16);
        ((uint2*)xb)[i] = o;
    }
}

// ---------------- weights: transpose + bf16: Wb[m][n][k] = src[m][k][n] ----------------
__global__ __launch_bounds__(256) void k_wconv(const float* __restrict__ W1,
                                               const float* __restrict__ root1,
                                               const float* __restrict__ W2,
                                               const float* __restrict__ root2,
                                               unsigned short* __restrict__ Wb)
{
    int e = blockIdx.x * 256 + threadIdx.x;
    if (e >= 18 * 16384) return;
    int m = e >> 14;
    int rem = e & 16383;
    int n = rem >> 7;
    int k = rem & 127;
    float v;
    if (m < 8)       v = W1[m * 16384 + k * 128 + n];
    else if (m == 8) v = root1[k * 128 + n];
    else if (m < 17) v = W2[(m - 9) * 16384 + k * 128 + n];
    else             v = root2[k * 128 + n];
    Wb[e] = f2bf(v);
}

// ---------------- XCD-bound K-sliced gather + partial GEMM ----------------
// Slice s = 32 K-cols of X (3.2 MB -> L2-resident per XCD pair). Block binds to its
// actual XCD via s_getreg(HW_REG_XCC_ID); tiles distributed by per-slice atomic
// tickets with steal fallback (correct under ANY XCD mapping). Per (slice, 64-row
// tile): predicated gather (8 lanes/row, one 64B line per edge), K=32 MFMA with W
// from L2, bf16 partial P[s][lrow][128].
__global__ __launch_bounds__(512) void k_gather(const unsigned short* __restrict__ Xin,
                                                const unsigned short* __restrict__ Wb,
                                                const int* __restrict__ off,
                                                const unsigned short* __restrict__ srt16,
                                                unsigned short* __restrict__ P,
                                                int* __restrict__ tk,
                                                int row0)
{
    __shared__ unsigned short Al[8 * 64 * 40];   // 40 KB: plane stride 5120 B, row stride 80 B
    __shared__ int tile_sh;
    const int t = threadIdx.x;
    const int g = t >> 3, l8 = t & 7;            // gather: row / col-quad (4 bf16 each)
    const int lane = t & 63, w = t >> 6;
    const int rt = w >> 1, ch = w & 1;           // MFMA: 16-row tile / 64-col half
    const int cl = lane & 15, kq = lane >> 4;

    unsigned int xcc;
    asm volatile("s_getreg_b32 %0, hwreg(HW_REG_XCC_ID)" : "=s"(xcc));
    const int pref = (int)((xcc >> 1) & 3);

    for (int sit = 0; sit < 4; ++sit) {
        const int s = (pref + sit) & 3;
        const int ks0 = s * 32;
        for (;;) {
            __syncthreads();                     // protect Al + tile_sh from prev iter
            if (t == 0) tile_sh = atomicAdd(&tk[s], 1);
            __syncthreads();
            const int tile = tile_sh;
            if (tile >= HT64) break;
            const int grow0 = row0 + tile * 64;

            // ---- gather: row grow0+g, slice cols; predicated 4-deep per relation ----
            uint2 pk[8];
            const int row = grow0 + g;
            if (row < NN) {
                const int ob = row * 8;
                int o0 = off[ob],     o1 = off[ob + 1], o2 = off[ob + 2];
                int o3 = off[ob + 3], o4 = off[ob + 4], o5 = off[ob + 5];
                int o6 = off[ob + 6], o7 = off[ob + 7], o8 = off[ob + 8];
                const unsigned short* Xs = Xin + ks0 + l8 * 4;

#define REL(MM, SS, EE)                                                          \
    {                                                                            \
        int sE = (SS); int c = (EE) - (SS);                                      \
        int i0 = 0, i1 = 0, i2 = 0, i3 = 0;                                      \
        if (c > 0) i0 = srt16[sE];                                               \
        if (c > 1) i1 = srt16[sE + 1];                                           \
        if (c > 2) i2 = srt16[sE + 2];                                           \
        if (c > 3) i3 = srt16[sE + 3];                                           \
        uint2 u0 = {0,0}, u1 = {0,0}, u2 = {0,0}, u3 = {0,0};                    \
        if (c > 0) u0 = *(const uint2*)(Xs + (size_t)i0 * 128);                  \
        if (c > 1) u1 = *(const uint2*)(Xs + (size_t)i1 * 128);                  \
        if (c > 2) u2 = *(const uint2*)(Xs + (size_t)i2 * 128);                  \
        if (c > 3) u3 = *(const uint2*)(Xs + (size_t)i3 * 128);                  \
        float a0 = bflo(u0.x) + bflo(u1.x) + bflo(u2.x) + bflo(u3.x);            \
        float a1 = bfhi(u0.x) + bfhi(u1.x) + bfhi(u2.x) + bfhi(u3.x);            \
        float a2 = bflo(u0.y) + bflo(u1.y) + bflo(u2.y) + bflo(u3.y);            \
        float a3 = bfhi(u0.y) + bfhi(u1.y) + bfhi(u2.y) + bfhi(u3.y);            \
        for (int k = 4; k < c; k++) {                                            \
            int ii = srt16[sE + k];                                              \
            uint2 uu = *(const uint2*)(Xs + (size_t)ii * 128);                   \
            a0 += bflo(uu.x); a1 += bfhi(uu.x);                                  \
            a2 += bflo(uu.y); a3 += bfhi(uu.y);                                  \
        }                                                                        \
        float invc = 1.0f / (float)(c > 1 ? c : 1);                              \
        pk[MM].x = (unsigned int)f2bf(a0 * invc) | ((unsigned int)f2bf(a1 * invc) << 16); \
        pk[MM].y = (unsigned int)f2bf(a2 * invc) | ((unsigned int)f2bf(a3 * invc) << 16); \
    }
                REL(0, o0, o1) REL(1, o1, o2) REL(2, o2, o3) REL(3, o3, o4)
                REL(4, o4, o5) REL(5, o5, o6) REL(6, o6, o7) REL(7, o7, o8)
#undef REL
            } else {
                #pragma unroll
                for (int m = 0; m < 8; m++) pk[m] = uint2{0u, 0u};
            }
            #pragma unroll
            for (int m = 0; m < 8; m++)
                *(uint2*)((char*)Al + m * 5120 + g * 80 + l8 * 8) = pk[m];
            __syncthreads();

            // ---- K=32 partial MFMA: 9 matrices, W direct from L2 ----
            f32x4 acc[4];
            #pragma unroll
            for (int ct = 0; ct < 4; ct++) acc[ct] = f32x4{0.f, 0.f, 0.f, 0.f};
            const int arow = rt * 16 + cl;
            #pragma unroll
            for (int m = 0; m < 8; m++) {
                short8 af = *(const short8*)((const char*)Al + m * 5120 + arow * 80 + kq * 16);
                #pragma unroll
                for (int ct = 0; ct < 4; ct++) {
                    int n = ch * 64 + ct * 16 + cl;
                    short8 bfr = *(const short8*)(Wb + (size_t)m * 16384 + n * 128 + ks0 + kq * 8);
                    acc[ct] = __builtin_amdgcn_mfma_f32_16x16x32_bf16(af, bfr, acc[ct], 0, 0, 0);
                }
            }
            {   // root term: A straight from global (slice cols)
                int rg = grow0 + arow;
                short8 af = short8{0,0,0,0,0,0,0,0};
                if (rg < NN)
                    af = *(const short8*)(Xin + (size_t)rg * 128 + ks0 + kq * 8);
                #pragma unroll
                for (int ct = 0; ct < 4; ct++) {
                    int n = ch * 64 + ct * 16 + cl;
                    short8 bfr = *(const short8*)(Wb + (size_t)8 * 16384 + n * 128 + ks0 + kq * 8);
                    acc[ct] = __builtin_amdgcn_mfma_f32_16x16x32_bf16(af, bfr, acc[ct], 0, 0, 0);
                }
            }

            // ---- store bf16 partial ----
            #pragma unroll
            for (int ct = 0; ct < 4; ct++) {
                int col = ch * 64 + ct * 16 + cl;
                #pragma unroll
                for (int j = 0; j < 4; j++) {
                    int lrow = tile * 64 + rt * 16 + kq * 4 + j;
                    P[((size_t)s * HROWS + lrow) * 128 + col] = f2bf(acc[ct][j]);
                }
            }
        }
    }
}

// ---------------- reduce 4 slice-partials + bias; relu->bf16 | L2-norm->f32 ----------------
__global__ __launch_bounds__(256) void k_reduce(const unsigned short* __restrict__ P,
                                                const float* __restrict__ bias,
                                                unsigned short* __restrict__ out_bf,
                                                float* __restrict__ out_f,
                                                int row0, int mode)
{
    int lr = blockIdx.x * 4 + (threadIdx.x >> 6);
    int row = row0 + lr;
    if (lr >= HROWS || row >= NN) return;
    int lane = threadIdx.x & 63;
    int col = lane * 2;
    float sx = 0.f, sy = 0.f;
    #pragma unroll
    for (int s = 0; s < 4; s++) {
        unsigned int u = *(const unsigned int*)(P + ((size_t)s * HROWS + lr) * 128 + col);
        sx += bflo(u); sy += bfhi(u);
    }
    float2 bb = *(const float2*)(bias + col);
    sx += bb.x; sy += bb.y;
    if (mode == 0) {
        sx = fmaxf(sx, 0.f); sy = fmaxf(sy, 0.f);
        unsigned int o = (unsigned int)f2bf(sx) | ((unsigned int)f2bf(sy) << 16);
        *(unsigned int*)(out_bf + (size_t)row * 128 + col) = o;
    } else {
        float ss = sx * sx + sy * sy;
        #pragma unroll
        for (int o = 32; o > 0; o >>= 1) ss += __shfl_xor(ss, o);
        float inv = 1.0f / fmaxf(sqrtf(ss), 1e-12f);
        float2 o2; o2.x = sx * inv; o2.y = sy * inv;
        *(float2*)(out_f + (size_t)row * 128 + col) = o2;
    }
}

extern "C" void kernel_launch(void* const* d_in, const int* in_sizes, int n_in,
                              void* d_out, int out_size, void* d_ws, size_t ws_size,
                              hipStream_t stream)
{
    const float* x     = (const float*)d_in[0];
    const int*   ei    = (const int*)d_in[1];   // [2, E]
    const int*   et    = (const int*)d_in[2];   // [E]
    const float* W1    = (const float*)d_in[3];
    const float* root1 = (const float*)d_in[4];
    const float* b1    = (const float*)d_in[5];
    const float* W2    = (const float*)d_in[6];
    const float* root2 = (const float*)d_in[7];
    const float* b2    = (const float*)d_in[8];
    float* out = (float*)d_out;

    char* ws = (char*)d_ws;
    int* tk    = (int*)ws;                                  // 16 tickets (4 passes x 4 slices)
    int* cnt   = tk + 16;                                   // MB ints
    int* off   = cnt + MB;                                  // MB+1 ints
    int* bsum  = off + MB + 1;                              // 256
    int* carry = bsum + 256;                                // 256
    unsigned short* rank16 = (unsigned short*)(carry + 256);        // NE u16
    unsigned short* srt16  = rank16 + NE;                           // NE u16
    unsigned short* Xb     = srt16 + NE;                            // NN*128 bf16
    unsigned short* hb     = Xb + (size_t)NN * DD;                  // NN*128 bf16
    unsigned short* Wb     = hb + (size_t)NN * DD;                  // 18*16384 bf16
    unsigned short* P      = Wb + (size_t)18 * 16384;               // 4*HROWS*128 bf16 (25.6 MB)

    hipMemsetAsync(tk, 0, (size_t)(16 + MB) * 4, stream);   // tickets + cnt

    k_count<<<(NE + 255) / 256, 256, 0, stream>>>(ei, et, cnt, rank16);
    k_scan1<<<NBLK, 256, 0, stream>>>(cnt, off, bsum);
    k_scan2<<<1, 256, 0, stream>>>(bsum, carry);
    k_scan3<<<NBLK, 256, 0, stream>>>(off, carry);
    k_place<<<(NE + 255) / 256, 256, 0, stream>>>(ei, et, off, rank16, srt16);

    k_tobf16<<<(NN * DD / 4 + 255) / 256, 256, 0, stream>>>(x, Xb, NN * DD / 4);
    k_wconv<<<(18 * 16384 + 255) / 256, 256, 0, stream>>>(W1, root1, W2, root2, Wb);

    const int g_grid = 1568;
    const int r_grid = (HROWS + 3) / 4;   // 6256

    // ---- layer 1: hb = relu(x@root1 + b1 + sum_r mean_r(x)@W1r) ----
    for (int h = 0; h < 2; h++) {
        k_gather<<<g_grid, 512, 0, stream>>>(Xb, Wb, off, srt16, P, tk + h * 4, h * HROWS);
        k_reduce<<<r_grid, 256, 0, stream>>>(P, b1, hb, nullptr, h * HROWS, 0);
    }
    // ---- layer 2: out = normalize(hb@root2 + b2 + sum_r mean_r(hb)@W2r) ----
    for (int h = 0; h < 2; h++) {
        k_gather<<<g_grid, 512, 0, stream>>>(hb, Wb + (size_t)9 * 16384, off, srt16, P, tk + 8 + h * 4, h * HROWS);
        k_reduce<<<r_grid, 256, 0, stream>>>(P, b2, nullptr, out, h * HROWS, 1);
    }
}

// Round 13
// 898.962 us; speedup vs baseline: 1.0617x; 1.0617x over previous
//
#include <hip/hip_runtime.h>

#define NN 50000
#define NE 800000
#define DD 128
#define RR 8
#define MB (NN * RR)          // 400000 buckets keyed by (dst, r)
#define SCAN_BLK 2048
#define NBLK ((MB + SCAN_BLK - 1) / SCAN_BLK)   // 196

#define HT64 391              // 64-row tiles per half
#define HROWS (HT64 * 64)     // 25024 rows per half
#define SL32 ((size_t)NN * 32)   // elements per slice table

typedef __attribute__((ext_vector_type(8))) short short8;
typedef __attribute__((ext_vector_type(4))) float f32x4;

__device__ __forceinline__ unsigned short f2bf(float f)
{
    unsigned int u = __float_as_uint(f);
    u = (u + 0x7FFFu + ((u >> 16) & 1u)) >> 16;   // RNE
    return (unsigned short)u;
}
__device__ __forceinline__ float bflo(unsigned int p) { return __uint_as_float(p << 16); }
__device__ __forceinline__ float bfhi(unsigned int p) { return __uint_as_float(p & 0xFFFF0000u); }

// ---------------- count per (dst, relation); atomic return = edge rank ----------------
__global__ __launch_bounds__(256) void k_count(const int* __restrict__ ei,
                                               const int* __restrict__ et,
                                               int* __restrict__ cnt,
                                               unsigned short* __restrict__ rank16)
{
    int e = blockIdx.x * 256 + threadIdx.x;
    if (e < NE) {
        int r = et[e];
        int dst = ei[NE + e];
        int old = atomicAdd(&cnt[dst * RR + r], 1);
        rank16[e] = (unsigned short)old;
    }
}

// ---------------- exclusive scan over cnt -> off ----------------
__global__ __launch_bounds__(256) void k_scan1(const int* __restrict__ cnt,
                                               int* __restrict__ off,
                                               int* __restrict__ bsum)
{
    __shared__ int lds[256];
    int t = threadIdx.x;
    int base = blockIdx.x * SCAN_BLK + t * 8;
    int v[8], s = 0;
    #pragma unroll
    for (int j = 0; j < 8; j++) {
        int idx = base + j;
        v[j] = (idx < MB) ? cnt[idx] : 0;
        s += v[j];
    }
    lds[t] = s;
    __syncthreads();
    for (int d = 1; d < 256; d <<= 1) {
        int u = (t >= d) ? lds[t - d] : 0;
        __syncthreads();
        lds[t] += u;
        __syncthreads();
    }
    if (t == 255) bsum[blockIdx.x] = lds[255];
    int run = lds[t] - s;
    #pragma unroll
    for (int j = 0; j < 8; j++) {
        int idx = base + j;
        if (idx < MB) off[idx] = run;
        run += v[j];
    }
}

__global__ __launch_bounds__(256) void k_scan2(const int* __restrict__ bsum,
                                               int* __restrict__ carry)
{
    __shared__ int lds[256];
    int t = threadIdx.x;
    int s = (t < NBLK) ? bsum[t] : 0;
    lds[t] = s;
    __syncthreads();
    for (int d = 1; d < 256; d <<= 1) {
        int u = (t >= d) ? lds[t - d] : 0;
        __syncthreads();
        lds[t] += u;
        __syncthreads();
    }
    if (t < NBLK) carry[t] = lds[t] - s;
}

__global__ __launch_bounds__(256) void k_scan3(int* __restrict__ off,
                                               const int* __restrict__ carry)
{
    int c = carry[blockIdx.x];
    int base = blockIdx.x * SCAN_BLK + threadIdx.x * 8;
    #pragma unroll
    for (int j = 0; j < 8; j++) {
        int idx = base + j;
        if (idx < MB) off[idx] += c;
    }
    if (blockIdx.x == 0 && threadIdx.x == 0) off[MB] = NE;   // sentinel
}

// ---------------- place edges into CSR slots: NO atomics (rank precomputed) ----------------
__global__ __launch_bounds__(256) void k_place(const int* __restrict__ ei,
                                               const int* __restrict__ et,
                                               const int* __restrict__ off,
                                               const unsigned short* __restrict__ rank16,
                                               unsigned short* __restrict__ srt16)
{
    int e = blockIdx.x * 256 + threadIdx.x;
    if (e < NE) {
        int b = ei[NE + e] * RR + et[e];
        srt16[off[b] + (int)rank16[e]] = (unsigned short)ei[e];   // src < 50000 < 65536
    }
}

// ---------------- f32 -> bf16, SLICE-MAJOR: Xs[s][row][32] (contiguous 3.2MB tables) ----------------
__global__ __launch_bounds__(256) void k_tobf16s(const float* __restrict__ x,
                                                 unsigned short* __restrict__ Xs)
{
    int i = blockIdx.x * 256 + threadIdx.x;   // one float4 (4 cols) per thread
    if (i >= NN * 32) return;
    int row = i >> 5;
    int cq = i & 31;            // col-quad: cols 4*cq..4*cq+3
    float4 v = *(const float4*)(x + (size_t)row * 128 + cq * 4);
    uint2 o;
    o.x = (unsigned int)f2bf(v.x) | ((unsigned int)f2bf(v.y) << 16);
    o.y = (unsigned int)f2bf(v.z) | ((unsigned int)f2bf(v.w) << 16);
    int s = cq >> 3;
    *(uint2*)(Xs + (size_t)s * SL32 + (size_t)row * 32 + (cq & 7) * 4) = o;
}

// ---------------- weights: transpose + bf16: Wb[m][n][k] = src[m][k][n] ----------------
__global__ __launch_bounds__(256) void k_wconv(const float* __restrict__ W1,
                                               const float* __restrict__ root1,
                                               const float* __restrict__ W2,
                                               const float* __restrict__ root2,
                                               unsigned short* __restrict__ Wb)
{
    int e = blockIdx.x * 256 + threadIdx.x;
    if (e >= 18 * 16384) return;
    int m = e >> 14;
    int rem = e & 16383;
    int n = rem >> 7;
    int k = rem & 127;
    float v;
    if (m < 8)       v = W1[m * 16384 + k * 128 + n];
    else if (m == 8) v = root1[k * 128 + n];
    else if (m < 17) v = W2[(m - 9) * 16384 + k * 128 + n];
    else             v = root2[k * 128 + n];
    Wb[e] = f2bf(v);
}

// ---------------- XCD-bound K-sliced gather + partial GEMM (slice-major X) ----------------
__global__ __launch_bounds__(512) void k_gather(const unsigned short* __restrict__ Xs,
                                                const unsigned short* __restrict__ Wb,
                                                const int* __restrict__ off,
                                                const unsigned short* __restrict__ srt16,
                                                unsigned short* __restrict__ P,
                                                int* __restrict__ tk,
                                                int row0)
{
    __shared__ unsigned short Al[8 * 64 * 40];   // 40 KB: plane stride 5120 B, row stride 80 B
    __shared__ int tile_sh;
    const int t = threadIdx.x;
    const int g = t >> 3, l8 = t & 7;            // gather: row / col-quad (4 bf16 each)
    const int lane = t & 63, w = t >> 6;
    const int rt = w >> 1, ch = w & 1;           // MFMA: 16-row tile / 64-col half
    const int cl = lane & 15, kq = lane >> 4;

    unsigned int xcc;
    asm volatile("s_getreg_b32 %0, hwreg(HW_REG_XCC_ID)" : "=s"(xcc));
    const int pref = (int)((xcc >> 1) & 3);

    for (int sit = 0; sit < 4; ++sit) {
        const int s = (pref + sit) & 3;
        const unsigned short* Xt = Xs + (size_t)s * SL32;   // contiguous 3.2 MB slice table
        const int ks0 = s * 32;
        for (;;) {
            __syncthreads();                     // protect Al + tile_sh from prev iter
            if (t == 0) tile_sh = atomicAdd(&tk[s], 1);
            __syncthreads();
            const int tile = tile_sh;
            if (tile >= HT64) break;
            const int grow0 = row0 + tile * 64;

            // ---- gather: row grow0+g, slice cols; predicated 4-deep per relation ----
            uint2 pk[8];
            const int row = grow0 + g;
            if (row < NN) {
                const int ob = row * 8;
                int o0 = off[ob],     o1 = off[ob + 1], o2 = off[ob + 2];
                int o3 = off[ob + 3], o4 = off[ob + 4], o5 = off[ob + 5];
                int o6 = off[ob + 6], o7 = off[ob + 7], o8 = off[ob + 8];
                const unsigned short* Xp = Xt + l8 * 4;

#define REL(MM, SS, EE)                                                          \
    {                                                                            \
        int sE = (SS); int c = (EE) - (SS);                                      \
        int i0 = 0, i1 = 0, i2 = 0, i3 = 0;                                      \
        if (c > 0) i0 = srt16[sE];                                               \
        if (c > 1) i1 = srt16[sE + 1];                                           \
        if (c > 2) i2 = srt16[sE + 2];                                           \
        if (c > 3) i3 = srt16[sE + 3];                                           \
        uint2 u0 = {0,0}, u1 = {0,0}, u2 = {0,0}, u3 = {0,0};                    \
        if (c > 0) u0 = *(const uint2*)(Xp + (size_t)i0 * 32);                   \
        if (c > 1) u1 = *(const uint2*)(Xp + (size_t)i1 * 32);                   \
        if (c > 2) u2 = *(const uint2*)(Xp + (size_t)i2 * 32);                   \
        if (c > 3) u3 = *(const uint2*)(Xp + (size_t)i3 * 32);                   \
        float a0 = bflo(u0.x) + bflo(u1.x) + bflo(u2.x) + bflo(u3.x);            \
        float a1 = bfhi(u0.x) + bfhi(u1.x) + bfhi(u2.x) + bfhi(u3.x);            \
        float a2 = bflo(u0.y) + bflo(u1.y) + bflo(u2.y) + bflo(u3.y);            \
        float a3 = bfhi(u0.y) + bfhi(u1.y) + bfhi(u2.y) + bfhi(u3.y);            \
        for (int k = 4; k < c; k++) {                                            \
            int ii = srt16[sE + k];                                              \
            uint2 uu = *(const uint2*)(Xp + (size_t)ii * 32);                    \
            a0 += bflo(uu.x); a1 += bfhi(uu.x);                                  \
            a2 += bflo(uu.y); a3 += bfhi(uu.y);                                  \
        }                                                                        \
        float invc = 1.0f / (float)(c > 1 ? c : 1);                              \
        pk[MM].x = (unsigned int)f2bf(a0 * invc) | ((unsigned int)f2bf(a1 * invc) << 16); \
        pk[MM].y = (unsigned int)f2bf(a2 * invc) | ((unsigned int)f2bf(a3 * invc) << 16); \
    }
                REL(0, o0, o1) REL(1, o1, o2) REL(2, o2, o3) REL(3, o3, o4)
                REL(4, o4, o5) REL(5, o5, o6) REL(6, o6, o7) REL(7, o7, o8)
#undef REL
            } else {
                #pragma unroll
                for (int m = 0; m < 8; m++) pk[m] = uint2{0u, 0u};
            }
            #pragma unroll
            for (int m = 0; m < 8; m++)
                *(uint2*)((char*)Al + m * 5120 + g * 80 + l8 * 8) = pk[m];
            __syncthreads();

            // ---- K=32 partial MFMA: 9 matrices, W direct from L2 ----
            f32x4 acc[4];
            #pragma unroll
            for (int ct = 0; ct < 4; ct++) acc[ct] = f32x4{0.f, 0.f, 0.f, 0.f};
            const int arow = rt * 16 + cl;
            #pragma unroll
            for (int m = 0; m < 8; m++) {
                short8 af = *(const short8*)((const char*)Al + m * 5120 + arow * 80 + kq * 16);
                #pragma unroll
                for (int ct = 0; ct < 4; ct++) {
                    int n = ch * 64 + ct * 16 + cl;
                    short8 bfr = *(const short8*)(Wb + (size_t)m * 16384 + n * 128 + ks0 + kq * 8);
                    acc[ct] = __builtin_amdgcn_mfma_f32_16x16x32_bf16(af, bfr, acc[ct], 0, 0, 0);
                }
            }
            {   // root term: A from slice table
                int rg = grow0 + arow;
                short8 af = short8{0,0,0,0,0,0,0,0};
                if (rg < NN)
                    af = *(const short8*)(Xt + (size_t)rg * 32 + kq * 8);
                #pragma unroll
                for (int ct = 0; ct < 4; ct++) {
                    int n = ch * 64 + ct * 16 + cl;
                    short8 bfr = *(const short8*)(Wb + (size_t)8 * 16384 + n * 128 + ks0 + kq * 8);
                    acc[ct] = __builtin_amdgcn_mfma_f32_16x16x32_bf16(af, bfr, acc[ct], 0, 0, 0);
                }
            }

            // ---- store bf16 partial ----
            #pragma unroll
            for (int ct = 0; ct < 4; ct++) {
                int col = ch * 64 + ct * 16 + cl;
                #pragma unroll
                for (int j = 0; j < 4; j++) {
                    int lrow = tile * 64 + rt * 16 + kq * 4 + j;
                    P[((size_t)s * HROWS + lrow) * 128 + col] = f2bf(acc[ct][j]);
                }
            }
        }
    }
}

// ---------------- reduce 4 slice-partials + bias ----------------
// mode 0: relu -> SLICE-MAJOR bf16 (hs tables).  mode 1: L2-norm -> f32 out.
__global__ __launch_bounds__(256) void k_reduce(const unsigned short* __restrict__ P,
                                                const float* __restrict__ bias,
                                                unsigned short* __restrict__ out_sl,
                                                float* __restrict__ out_f,
                                                int row0, int mode)
{
    int lr = blockIdx.x * 4 + (threadIdx.x >> 6);
    int row = row0 + lr;
    if (lr >= HROWS || row >= NN) return;
    int lane = threadIdx.x & 63;
    int col = lane * 2;
    float sx = 0.f, sy = 0.f;
    #pragma unroll
    for (int s = 0; s < 4; s++) {
        unsigned int u = *(const unsigned int*)(P + ((size_t)s * HROWS + lr) * 128 + col);
        sx += bflo(u); sy += bfhi(u);
    }
    float2 bb = *(const float2*)(bias + col);
    sx += bb.x; sy += bb.y;
    if (mode == 0) {
        sx = fmaxf(sx, 0.f); sy = fmaxf(sy, 0.f);
        unsigned int o = (unsigned int)f2bf(sx) | ((unsigned int)f2bf(sy) << 16);
        int s = lane >> 4;                       // slice of these 2 cols
        *(unsigned int*)(out_sl + (size_t)s * SL32 + (size_t)row * 32 + (lane & 15) * 2) = o;
    } else {
        float ss = sx * sx + sy * sy;
        #pragma unroll
        for (int o = 32; o > 0; o >>= 1) ss += __shfl_xor(ss, o);
        float inv = 1.0f / fmaxf(sqrtf(ss), 1e-12f);
        float2 o2; o2.x = sx * inv; o2.y = sy * inv;
        *(float2*)(out_f + (size_t)row * 128 + col) = o2;
    }
}

extern "C" void kernel_launch(void* const* d_in, const int* in_sizes, int n_in,
                              void* d_out, int out_size, void* d_ws, size_t ws_size,
                              hipStream_t stream)
{
    const float* x     = (const float*)d_in[0];
    const int*   ei    = (const int*)d_in[1];   // [2, E]
    const int*   et    = (const int*)d_in[2];   // [E]
    const float* W1    = (const float*)d_in[3];
    const float* root1 = (const float*)d_in[4];
    const float* b1    = (const float*)d_in[5];
    const float* W2    = (const float*)d_in[6];
    const float* root2 = (const float*)d_in[7];
    const float* b2    = (const float*)d_in[8];
    float* out = (float*)d_out;

    char* ws = (char*)d_ws;
    int* tk    = (int*)ws;                                  // 16 tickets (4 passes x 4 slices)
    int* cnt   = tk + 16;                                   // MB ints
    int* off   = cnt + MB;                                  // MB+1 ints
    int* bsum  = off + MB + 1;                              // 256
    int* carry = bsum + 256;                                // 256
    unsigned short* rank16 = (unsigned short*)(carry + 256);        // NE u16
    unsigned short* srt16  = rank16 + NE;                           // NE u16
    unsigned short* Xs     = srt16 + NE;                            // 4 slice tables (12.8 MB)
    unsigned short* hs     = Xs + (size_t)NN * DD;                  // 4 slice tables (12.8 MB)
    unsigned short* Wb     = hs + (size_t)NN * DD;                  // 18*16384 bf16
    unsigned short* P      = Wb + (size_t)18 * 16384;               // 4*HROWS*128 bf16 (25.6 MB)

    hipMemsetAsync(tk, 0, (size_t)(16 + MB) * 4, stream);   // tickets + cnt

    k_count<<<(NE + 255) / 256, 256, 0, stream>>>(ei, et, cnt, rank16);
    k_scan1<<<NBLK, 256, 0, stream>>>(cnt, off, bsum);
    k_scan2<<<1, 256, 0, stream>>>(bsum, carry);
    k_scan3<<<NBLK, 256, 0, stream>>>(off, carry);
    k_place<<<(NE + 255) / 256, 256, 0, stream>>>(ei, et, off, rank16, srt16);

    k_tobf16s<<<(NN * 32 + 255) / 256, 256, 0, stream>>>(x, Xs);
    k_wconv<<<(18 * 16384 + 255) / 256, 256, 0, stream>>>(W1, root1, W2, root2, Wb);

    const int g_grid = 1568;
    const int r_grid = (HROWS + 3) / 4;   // 6256

    // ---- layer 1: hs = relu(x@root1 + b1 + sum_r mean_r(x)@W1r), slice-major ----
    for (int h = 0; h < 2; h++) {
        k_gather<<<g_grid, 512, 0, stream>>>(Xs, Wb, off, srt16, P, tk + h * 4, h * HROWS);
        k_reduce<<<r_grid, 256, 0, stream>>>(P, b1, hs, nullptr, h * HROWS, 0);
    }
    // ---- layer 2: out = normalize(hs@root2 + b2 + sum_r mean_r(hs)@W2r) ----
    for (int h = 0; h < 2; h++) {
        k_gather<<<g_grid, 512, 0, stream>>>(hs, Wb + (size_t)9 * 16384, off, srt16, P, tk + 8 + h * 4, h * HROWS);
        k_reduce<<<r_grid, 256, 0, stream>>>(P, b2, nullptr, out, h * HROWS, 1);
    }
}

// Round 14
// 488.950 us; speedup vs baseline: 1.9519x; 1.8386x over previous
//
#include <hip/hip_runtime.h>

#define NN 50000
#define NE 800000
#define DD 128
#define RR 8
#define MB (NN * RR)          // 400000 buckets keyed by (dst, r)
#define SCAN_BLK 2048
#define NBLK ((MB + SCAN_BLK - 1) / SCAN_BLK)   // 196

#define HT64 391              // 64-row tiles per half
#define HROWS (HT64 * 64)     // 25024 rows per half
#define SL32 ((size_t)NN * 32)   // elements per slice table

typedef __attribute__((ext_vector_type(8))) short short8;
typedef __attribute__((ext_vector_type(4))) float f32x4;

__device__ __forceinline__ unsigned short f2bf(float f)
{
    unsigned int u = __float_as_uint(f);
    u = (u + 0x7FFFu + ((u >> 16) & 1u)) >> 16;   // RNE
    return (unsigned short)u;
}
__device__ __forceinline__ float bflo(unsigned int p) { return __uint_as_float(p << 16); }
__device__ __forceinline__ float bfhi(unsigned int p) { return __uint_as_float(p & 0xFFFF0000u); }

// ---------------- count per (dst, relation); atomic return = edge rank ----------------
__global__ __launch_bounds__(256) void k_count(const int* __restrict__ ei,
                                               const int* __restrict__ et,
                                               int* __restrict__ cnt,
                                               unsigned short* __restrict__ rank16)
{
    int e = blockIdx.x * 256 + threadIdx.x;
    if (e < NE) {
        int r = et[e];
        int dst = ei[NE + e];
        int old = atomicAdd(&cnt[dst * RR + r], 1);
        rank16[e] = (unsigned short)old;
    }
}

// ---------------- exclusive scan over cnt -> off ----------------
__global__ __launch_bounds__(256) void k_scan1(const int* __restrict__ cnt,
                                               int* __restrict__ off,
                                               int* __restrict__ bsum)
{
    __shared__ int lds[256];
    int t = threadIdx.x;
    int base = blockIdx.x * SCAN_BLK + t * 8;
    int v[8], s = 0;
    #pragma unroll
    for (int j = 0; j < 8; j++) {
        int idx = base + j;
        v[j] = (idx < MB) ? cnt[idx] : 0;
        s += v[j];
    }
    lds[t] = s;
    __syncthreads();
    for (int d = 1; d < 256; d <<= 1) {
        int u = (t >= d) ? lds[t - d] : 0;
        __syncthreads();
        lds[t] += u;
        __syncthreads();
    }
    if (t == 255) bsum[blockIdx.x] = lds[255];
    int run = lds[t] - s;
    #pragma unroll
    for (int j = 0; j < 8; j++) {
        int idx = base + j;
        if (idx < MB) off[idx] = run;
        run += v[j];
    }
}

__global__ __launch_bounds__(256) void k_scan2(const int* __restrict__ bsum,
                                               int* __restrict__ carry)
{
    __shared__ int lds[256];
    int t = threadIdx.x;
    int s = (t < NBLK) ? bsum[t] : 0;
    lds[t] = s;
    __syncthreads();
    for (int d = 1; d < 256; d <<= 1) {
        int u = (t >= d) ? lds[t - d] : 0;
        __syncthreads();
        lds[t] += u;
        __syncthreads();
    }
    if (t < NBLK) carry[t] = lds[t] - s;
}

__global__ __launch_bounds__(256) void k_scan3(int* __restrict__ off,
                                               const int* __restrict__ carry)
{
    int c = carry[blockIdx.x];
    int base = blockIdx.x * SCAN_BLK + threadIdx.x * 8;
    #pragma unroll
    for (int j = 0; j < 8; j++) {
        int idx = base + j;
        if (idx < MB) off[idx] += c;
    }
    if (blockIdx.x == 0 && threadIdx.x == 0) off[MB] = NE;   // sentinel
}

// ---------------- place edges into CSR slots: NO atomics (rank precomputed) ----------------
__global__ __launch_bounds__(256) void k_place(const int* __restrict__ ei,
                                               const int* __restrict__ et,
                                               const int* __restrict__ off,
                                               const unsigned short* __restrict__ rank16,
                                               unsigned short* __restrict__ srt16)
{
    int e = blockIdx.x * 256 + threadIdx.x;
    if (e < NE) {
        int b = ei[NE + e] * RR + et[e];
        srt16[off[b] + (int)rank16[e]] = (unsigned short)ei[e];   // src < 50000 < 65536
    }
}

// ---------------- f32 -> bf16, SLICE-MAJOR: Xs[s][row][32] (contiguous 3.2MB tables) ----------------
__global__ __launch_bounds__(256) void k_tobf16s(const float* __restrict__ x,
                                                 unsigned short* __restrict__ Xs)
{
    int i = blockIdx.x * 256 + threadIdx.x;   // one float4 (4 cols) per thread
    if (i >= NN * 32) return;
    int row = i >> 5;
    int cq = i & 31;            // col-quad: cols 4*cq..4*cq+3
    float4 v = *(const float4*)(x + (size_t)row * 128 + cq * 4);
    uint2 o;
    o.x = (unsigned int)f2bf(v.x) | ((unsigned int)f2bf(v.y) << 16);
    o.y = (unsigned int)f2bf(v.z) | ((unsigned int)f2bf(v.w) << 16);
    int s = cq >> 3;
    *(uint2*)(Xs + (size_t)s * SL32 + (size_t)row * 32 + (cq & 7) * 4) = o;
}

// ---------------- weights: transpose + bf16: Wb[m][n][k] = src[m][k][n] ----------------
__global__ __launch_bounds__(256) void k_wconv(const float* __restrict__ W1,
                                               const float* __restrict__ root1,
                                               const float* __restrict__ W2,
                                               const float* __restrict__ root2,
                                               unsigned short* __restrict__ Wb)
{
    int e = blockIdx.x * 256 + threadIdx.x;
    if (e >= 18 * 16384) return;
    int m = e >> 14;
    int rem = e & 16383;
    int n = rem >> 7;
    int k = rem & 127;
    float v;
    if (m < 8)       v = W1[m * 16384 + k * 128 + n];
    else if (m == 8) v = root1[k * 128 + n];
    else if (m < 17) v = W2[(m - 9) * 16384 + k * 128 + n];
    else             v = root2[k * 128 + n];
    Wb[e] = f2bf(v);
}

// ---------------- static XCD-aware K-sliced gather + partial GEMM (slice-major X) ----------------
// Grid 1568. Block b: slice s = (b&7)>>1 (blockIdx%8 -> XCD round-robin, m192-verified
// heuristic; locality-only, correctness mapping-independent), tile = (b>>3)*2 + (b&1).
// NO atomics, NO stealing: the slice's 3.2 MB table stays L2-resident on its XCD pair.
__global__ __launch_bounds__(512) void k_gather(const unsigned short* __restrict__ Xs,
                                                const unsigned short* __restrict__ Wb,
                                                const int* __restrict__ off,
                                                const unsigned short* __restrict__ srt16,
                                                unsigned short* __restrict__ P,
                                                int row0)
{
    __shared__ unsigned short Al[8 * 64 * 40];   // 40 KB: plane stride 5120 B, row stride 80 B
    const int b = blockIdx.x;
    const int s = (b & 7) >> 1;
    const int tile = (b >> 3) * 2 + (b & 1);
    if (tile >= HT64) return;
    const int t = threadIdx.x;
    const int g = t >> 3, l8 = t & 7;            // gather: row / col-quad (4 bf16 each)
    const int lane = t & 63, w = t >> 6;
    const int rt = w >> 1, ch = w & 1;           // MFMA: 16-row tile / 64-col half
    const int cl = lane & 15, kq = lane >> 4;

    const unsigned short* Xt = Xs + (size_t)s * SL32;   // contiguous 3.2 MB slice table
    const int ks0 = s * 32;
    const int grow0 = row0 + tile * 64;

    // ---- gather: row grow0+g, slice cols; predicated 4-deep per relation ----
    uint2 pk[8];
    const int row = grow0 + g;
    if (row < NN) {
        const int ob = row * 8;
        int o0 = off[ob],     o1 = off[ob + 1], o2 = off[ob + 2];
        int o3 = off[ob + 3], o4 = off[ob + 4], o5 = off[ob + 5];
        int o6 = off[ob + 6], o7 = off[ob + 7], o8 = off[ob + 8];
        const unsigned short* Xp = Xt + l8 * 4;

#define REL(MM, SS, EE)                                                          \
    {                                                                            \
        int sE = (SS); int c = (EE) - (SS);                                      \
        int i0 = 0, i1 = 0, i2 = 0, i3 = 0;                                      \
        if (c > 0) i0 = srt16[sE];                                               \
        if (c > 1) i1 = srt16[sE + 1];                                           \
        if (c > 2) i2 = srt16[sE + 2];                                           \
        if (c > 3) i3 = srt16[sE + 3];                                           \
        uint2 u0 = {0,0}, u1 = {0,0}, u2 = {0,0}, u3 = {0,0};                    \
        if (c > 0) u0 = *(const uint2*)(Xp + (size_t)i0 * 32);                   \
        if (c > 1) u1 = *(const uint2*)(Xp + (size_t)i1 * 32);                   \
        if (c > 2) u2 = *(const uint2*)(Xp + (size_t)i2 * 32);                   \
        if (c > 3) u3 = *(const uint2*)(Xp + (size_t)i3 * 32);                   \
        float a0 = bflo(u0.x) + bflo(u1.x) + bflo(u2.x) + bflo(u3.x);            \
        float a1 = bfhi(u0.x) + bfhi(u1.x) + bfhi(u2.x) + bfhi(u3.x);            \
        float a2 = bflo(u0.y) + bflo(u1.y) + bflo(u2.y) + bflo(u3.y);            \
        float a3 = bfhi(u0.y) + bfhi(u1.y) + bfhi(u2.y) + bfhi(u3.y);            \
        for (int k = 4; k < c; k++) {                                            \
            int ii = srt16[sE + k];                                              \
            uint2 uu = *(const uint2*)(Xp + (size_t)ii * 32);                    \
            a0 += bflo(uu.x); a1 += bfhi(uu.x);                                  \
            a2 += bflo(uu.y); a3 += bfhi(uu.y);                                  \
        }                                                                        \
        float invc = 1.0f / (float)(c > 1 ? c : 1);                              \
        pk[MM].x = (unsigned int)f2bf(a0 * invc) | ((unsigned int)f2bf(a1 * invc) << 16); \
        pk[MM].y = (unsigned int)f2bf(a2 * invc) | ((unsigned int)f2bf(a3 * invc) << 16); \
    }
        REL(0, o0, o1) REL(1, o1, o2) REL(2, o2, o3) REL(3, o3, o4)
        REL(4, o4, o5) REL(5, o5, o6) REL(6, o6, o7) REL(7, o7, o8)
#undef REL
    } else {
        #pragma unroll
        for (int m = 0; m < 8; m++) pk[m] = uint2{0u, 0u};
    }
    #pragma unroll
    for (int m = 0; m < 8; m++)
        *(uint2*)((char*)Al + m * 5120 + g * 80 + l8 * 8) = pk[m];
    __syncthreads();

    // ---- K=32 partial MFMA: 9 matrices, W direct from L2 ----
    f32x4 acc[4];
    #pragma unroll
    for (int ct = 0; ct < 4; ct++) acc[ct] = f32x4{0.f, 0.f, 0.f, 0.f};
    const int arow = rt * 16 + cl;
    #pragma unroll
    for (int m = 0; m < 8; m++) {
        short8 af = *(const short8*)((const char*)Al + m * 5120 + arow * 80 + kq * 16);
        #pragma unroll
        for (int ct = 0; ct < 4; ct++) {
            int n = ch * 64 + ct * 16 + cl;
            short8 bfr = *(const short8*)(Wb + (size_t)m * 16384 + n * 128 + ks0 + kq * 8);
            acc[ct] = __builtin_amdgcn_mfma_f32_16x16x32_bf16(af, bfr, acc[ct], 0, 0, 0);
        }
    }
    {   // root term: A from slice table
        int rg = grow0 + arow;
        short8 af = short8{0,0,0,0,0,0,0,0};
        if (rg < NN)
            af = *(const short8*)(Xt + (size_t)rg * 32 + kq * 8);
        #pragma unroll
        for (int ct = 0; ct < 4; ct++) {
            int n = ch * 64 + ct * 16 + cl;
            short8 bfr = *(const short8*)(Wb + (size_t)8 * 16384 + n * 128 + ks0 + kq * 8);
            acc[ct] = __builtin_amdgcn_mfma_f32_16x16x32_bf16(af, bfr, acc[ct], 0, 0, 0);
        }
    }

    // ---- store bf16 partial ----
    #pragma unroll
    for (int ct = 0; ct < 4; ct++) {
        int col = ch * 64 + ct * 16 + cl;
        #pragma unroll
        for (int j = 0; j < 4; j++) {
            int lrow = tile * 64 + rt * 16 + kq * 4 + j;
            P[((size_t)s * HROWS + lrow) * 128 + col] = f2bf(acc[ct][j]);
        }
    }
}

// ---------------- reduce 4 slice-partials + bias ----------------
// mode 0: relu -> SLICE-MAJOR bf16 (hs tables).  mode 1: L2-norm -> f32 out.
__global__ __launch_bounds__(256) void k_reduce(const unsigned short* __restrict__ P,
                                                const float* __restrict__ bias,
                                                unsigned short* __restrict__ out_sl,
                                                float* __restrict__ out_f,
                                                int row0, int mode)
{
    int lr = blockIdx.x * 4 + (threadIdx.x >> 6);
    int row = row0 + lr;
    if (lr >= HROWS || row >= NN) return;
    int lane = threadIdx.x & 63;
    int col = lane * 2;
    float sx = 0.f, sy = 0.f;
    #pragma unroll
    for (int s = 0; s < 4; s++) {
        unsigned int u = *(const unsigned int*)(P + ((size_t)s * HROWS + lr) * 128 + col);
        sx += bflo(u); sy += bfhi(u);
    }
    float2 bb = *(const float2*)(bias + col);
    sx += bb.x; sy += bb.y;
    if (mode == 0) {
        sx = fmaxf(sx, 0.f); sy = fmaxf(sy, 0.f);
        unsigned int o = (unsigned int)f2bf(sx) | ((unsigned int)f2bf(sy) << 16);
        int s = lane >> 4;                       // slice of these 2 cols
        *(unsigned int*)(out_sl + (size_t)s * SL32 + (size_t)row * 32 + (lane & 15) * 2) = o;
    } else {
        float ss = sx * sx + sy * sy;
        #pragma unroll
        for (int o = 32; o > 0; o >>= 1) ss += __shfl_xor(ss, o);
        float inv = 1.0f / fmaxf(sqrtf(ss), 1e-12f);
        float2 o2; o2.x = sx * inv; o2.y = sy * inv;
        *(float2*)(out_f + (size_t)row * 128 + col) = o2;
    }
}

extern "C" void kernel_launch(void* const* d_in, const int* in_sizes, int n_in,
                              void* d_out, int out_size, void* d_ws, size_t ws_size,
                              hipStream_t stream)
{
    const float* x     = (const float*)d_in[0];
    const int*   ei    = (const int*)d_in[1];   // [2, E]
    const int*   et    = (const int*)d_in[2];   // [E]
    const float* W1    = (const float*)d_in[3];
    const float* root1 = (const float*)d_in[4];
    const float* b1    = (const float*)d_in[5];
    const float* W2    = (const float*)d_in[6];
    const float* root2 = (const float*)d_in[7];
    const float* b2    = (const float*)d_in[8];
    float* out = (float*)d_out;

    char* ws = (char*)d_ws;
    int* cnt   = (int*)ws;                                  // MB ints
    int* off   = cnt + MB;                                  // MB+1 ints
    int* bsum  = off + MB + 1;                              // 256
    int* carry = bsum + 256;                                // 256
    unsigned short* rank16 = (unsigned short*)(carry + 256);        // NE u16
    unsigned short* srt16  = rank16 + NE;                           // NE u16
    unsigned short* Xs     = srt16 + NE;                            // 4 slice tables (12.8 MB)
    unsigned short* hs     = Xs + (size_t)NN * DD;                  // 4 slice tables (12.8 MB)
    unsigned short* Wb     = hs + (size_t)NN * DD;                  // 18*16384 bf16
    unsigned short* P      = Wb + (size_t)18 * 16384;               // 4*HROWS*128 bf16 (25.6 MB)

    hipMemsetAsync(cnt, 0, (size_t)MB * 4, stream);

    k_count<<<(NE + 255) / 256, 256, 0, stream>>>(ei, et, cnt, rank16);
    k_scan1<<<NBLK, 256, 0, stream>>>(cnt, off, bsum);
    k_scan2<<<1, 256, 0, stream>>>(bsum, carry);
    k_scan3<<<NBLK, 256, 0, stream>>>(off, carry);
    k_place<<<(NE + 255) / 256, 256, 0, stream>>>(ei, et, off, rank16, srt16);

    k_tobf16s<<<(NN * 32 + 255) / 256, 256, 0, stream>>>(x, Xs);
    k_wconv<<<(18 * 16384 + 255) / 256, 256, 0, stream>>>(W1, root1, W2, root2, Wb);

    const int g_grid = 1568;              // 196 q-steps x 8 (4 slices x 2 tile-lanes)
    const int r_grid = (HROWS + 3) / 4;   // 6256

    // ---- layer 1: hs = relu(x@root1 + b1 + sum_r mean_r(x)@W1r), slice-major ----
    for (int h = 0; h < 2; h++) {
        k_gather<<<g_grid, 512, 0, stream>>>(Xs, Wb, off, srt16, P, h * HROWS);
        k_reduce<<<r_grid, 256, 0, stream>>>(P, b1, hs, nullptr, h * HROWS, 0);
    }
    // ---- layer 2: out = normalize(hs@root2 + b2 + sum_r mean_r(hs)@W2r) ----
    for (int h = 0; h < 2; h++) {
        k_gather<<<g_grid, 512, 0, stream>>>(hs, Wb + (size_t)9 * 16384, off, srt16, P, h * HROWS);
        k_reduce<<<r_grid, 256, 0, stream>>>(P, b2, nullptr, out, h * HROWS, 1);
    }
}